// Round 10
// baseline (45.772 us; speedup 1.0000x reference)
//
#include <hip/hip_runtime.h>
#include <hip/hip_bf16.h>

// MLP_small_per_feature: per-feature MLP 1 -> 64 -> 64 -> 1, F=256, B=8192.
// v10: PURE REGISTER PIPELINE -- no LDS, no cross-lane ops, no barriers.
// Key trick: pack w2 with its OUTPUT rows permuted (o' below) so that the
// layer-2 MFMA's C/D output lands, lane-for-lane, in B-fragment k-slot
// order. relu+cvt of acc then directly feeds a THIRD MFMA computing the
// layer-3 dot product (A = w3 replicated across rows -> D = out[b] in every
// lane). This deletes the per-pass shuffles/LDS that rounds 1-9 proved to
// be the latency wall (v9's pairing win quantified it).
//
//   o'(16t + mt) = 32*(t>>1) + 8*(mt>>2) + 4*(t&1) + (mt&3)
//   => lane lg's acc values {t,r} hold h2[k], k = 32ks + 8lg + (4(t&1)+r)
//      = exactly the B-operand k-slots of mfma #3.
//
// MFMA 16x16x32_bf16 layout (verified rounds 1-9, absmax 0.031):
//   A: row m = lane&15, k = (lane>>4)*8 + i
//   B: col n = lane&15, k = (lane>>4)*8 + i
//   C/D: col n = lane&15, row m = (lane>>4)*4 + r
// Keep-trick store (verified v4/v6/v7): lane keeps pass p with p%4==lg;
// after each quad, full-wave store row = rb*128 + quad*64 + lane.
//
// Spill lessons: (256,8) forces VGPR=32 + spills (v6); tight caps serialize
// (v5/v8 signature: SGPR=96, FETCH~=WRITE~=170MB). Here: (256,2) = cap 256.

namespace {

constexpr int kF = 256;
constexpr int kH = 64;
constexpr int kB = 8192;

constexpr int kRowsPerWave = 128;
constexpr int kPasses      = kRowsPerWave / 16;        // 8
constexpr int kWavesTotal  = kF * (kB / kRowsPerWave); // 16384
constexpr int kThreads     = 256;                      // 4 independent waves
constexpr int kBlocks      = kWavesTotal / 4;          // 4096

using f32x4  = __attribute__((ext_vector_type(4))) float;
using bf16x4 = __attribute__((ext_vector_type(4))) __bf16;
using bf16x8 = __attribute__((ext_vector_type(8))) __bf16;

// ---- prep: pack w2 (o-permuted, bf16, fragment-major), b2 (o-permuted,
// C-layout order), w3 (bf16). One wave per feature. Runs once, ~2 us. ----
__global__ __launch_bounds__(256)
void pack_params(const float* __restrict__ w2, const float* __restrict__ b2,
                 const float* __restrict__ w3, __bf16* __restrict__ w2p,
                 float* __restrict__ b2p, __bf16* __restrict__ w3p)
{
  const int wid  = (int)threadIdx.x >> 6;
  const int lane = (int)threadIdx.x & 63;
  const int f    = (int)blockIdx.x * 4 + wid;
  const int l15  = lane & 15;
  const int lg   = lane >> 4;

  const float* w2f = w2 + (size_t)f * (kH * kH);
  #pragma unroll
  for (int t = 0; t < 4; ++t) {
    // permuted output row held by A-fragment row m = l15 of tile t
    const int o2 = 32 * (t >> 1) + 8 * (l15 >> 2) + 4 * (t & 1) + (l15 & 3);
    #pragma unroll
    for (int ks = 0; ks < 2; ++ks) {
      const float* p = w2f + o2 * kH + ks * 32 + lg * 8;
      const f32x4 lo = *reinterpret_cast<const f32x4*>(p);
      const f32x4 hi = *reinterpret_cast<const f32x4*>(p + 4);
      const bf16x8 v = __builtin_shufflevector(
          __builtin_convertvector(lo, bf16x4),
          __builtin_convertvector(hi, bf16x4), 0, 1, 2, 3, 4, 5, 6, 7);
      *reinterpret_cast<bf16x8*>(
          w2p + (((size_t)f * 8 + t * 2 + ks) * 64 + lane) * 8) = v;
    }
  }

  // b2p[f*64 + j], j = t*16 + lg*4 + r  <-  b2[f][o'(16t + 4lg + r)]
  {
    const int jt = lane >> 4, jlg = (lane >> 2) & 3, jr = lane & 3;
    const int o  = 32 * (jt >> 1) + 8 * jlg + 4 * (jt & 1) + jr;
    b2p[(size_t)f * kH + lane] = b2[(size_t)f * kH + o];
  }
  // w3p: plain bf16 copy (permutation made acc's k-slots identity in k)
  w3p[(size_t)f * kH + lane] = (__bf16)w3[(size_t)f * kH + lane];
}

__global__ __launch_bounds__(kThreads, 2)
void mlp_pf_v10(const float* __restrict__ x,
                const float* __restrict__ w1,
                const float* __restrict__ b1,
                const __bf16* __restrict__ w2p,
                const float* __restrict__ b2p,
                const __bf16* __restrict__ w3p,
                const float* __restrict__ b3,
                float* __restrict__ out)
{
  const int wid  = (int)threadIdx.x >> 6;
  const int lane = (int)threadIdx.x & 63;
  const int gw   = (int)blockIdx.x * 4 + wid;
  const int f    = gw >> 6;            // 64 consecutive waves share f (L2)
  const int rb   = gw & 63;
  const int l15  = lane & 15;
  const int lg   = lane >> 4;

  const int rowbase = rb * kRowsPerWave + l15;

  // ---- all 8 x gathers in flight immediately ----
  float xv[kPasses];
  #pragma unroll
  for (int p = 0; p < kPasses; ++p)
    xv[p] = x[(size_t)(rowbase + p * 16) * kF + f];

  // ---- w2 fragments: 8 coalesced 16B loads (L2-resident w2p) ----
  bf16x8 w2frag[4][2];
  {
    const __bf16* base = w2p + ((size_t)f * 8 * 64 + lane) * 8;
    #pragma unroll
    for (int t = 0; t < 4; ++t)
      #pragma unroll
      for (int ks = 0; ks < 2; ++ks)
        w2frag[t][ks] = *reinterpret_cast<const bf16x8*>(
            base + (size_t)(t * 2 + ks) * 64 * 8);
  }

  // ---- layer-1 params ----
  f32x4 w1v[2][2], b1v[2][2];
  #pragma unroll
  for (int ks = 0; ks < 2; ++ks) {
    const float* pw = w1 + f * kH + ks * 32 + lg * 8;
    const float* pb = b1 + f * kH + ks * 32 + lg * 8;
    w1v[ks][0] = *reinterpret_cast<const f32x4*>(pw);
    w1v[ks][1] = *reinterpret_cast<const f32x4*>(pw + 4);
    b1v[ks][0] = *reinterpret_cast<const f32x4*>(pb);
    b1v[ks][1] = *reinterpret_cast<const f32x4*>(pb + 4);
  }

  // ---- permuted b2 (C operand) and w3 A-fragments ----
  f32x4 b2c[4];
  #pragma unroll
  for (int t = 0; t < 4; ++t)
    b2c[t] = *reinterpret_cast<const f32x4*>(b2p + f * kH + t * 16 + lg * 4);
  bf16x8 w3f[2];
  #pragma unroll
  for (int ks = 0; ks < 2; ++ks)
    w3f[ks] = *reinterpret_cast<const bf16x8*>(w3p + f * kH + ks * 32 + lg * 8);
  const float b3v = b3[f];

  const f32x4 zero4 = {0.f, 0.f, 0.f, 0.f};
  float keep = 0.f;

  #pragma unroll
  for (int p = 0; p < kPasses; ++p) {
    // ---- layer 1: h1 = relu(x*w1 + b1) -> bf16 B-fragments ----
    bf16x8 h1frag[2];
    #pragma unroll
    for (int ks = 0; ks < 2; ++ks) {
      f32x4 a = w1v[ks][0] * xv[p] + b1v[ks][0];
      f32x4 b = w1v[ks][1] * xv[p] + b1v[ks][1];
      a = __builtin_elementwise_max(a, zero4);
      b = __builtin_elementwise_max(b, zero4);
      h1frag[ks] = __builtin_shufflevector(
          __builtin_convertvector(a, bf16x4),
          __builtin_convertvector(b, bf16x4), 0, 1, 2, 3, 4, 5, 6, 7);
    }

    // ---- layer 2 (C init = permuted b2): acc[t][r] = h2[32(t>>1)+8lg+4(t&1)+r] ----
    f32x4 acc[4];
    #pragma unroll
    for (int t = 0; t < 4; ++t) {
      acc[t] = __builtin_amdgcn_mfma_f32_16x16x32_bf16(
          w2frag[t][0], h1frag[0], b2c[t], 0, 0, 0);
      acc[t] = __builtin_amdgcn_mfma_f32_16x16x32_bf16(
          w2frag[t][1], h1frag[1], acc[t], 0, 0, 0);
    }

    // ---- relu + cvt: acc pairs form the B-fragments of the out-MFMA ----
    const f32x4 r0 = __builtin_elementwise_max(acc[0], zero4);
    const f32x4 r1 = __builtin_elementwise_max(acc[1], zero4);
    const f32x4 r2 = __builtin_elementwise_max(acc[2], zero4);
    const f32x4 r3 = __builtin_elementwise_max(acc[3], zero4);
    const bf16x8 h2f0 = __builtin_shufflevector(
        __builtin_convertvector(r0, bf16x4),
        __builtin_convertvector(r1, bf16x4), 0, 1, 2, 3, 4, 5, 6, 7);
    const bf16x8 h2f1 = __builtin_shufflevector(
        __builtin_convertvector(r2, bf16x4),
        __builtin_convertvector(r3, bf16x4), 0, 1, 2, 3, 4, 5, 6, 7);

    // ---- layer 3 via MFMA: D[m][b] = sum_k w3[k] h2[k][b] (rows replicated) ----
    f32x4 d = __builtin_amdgcn_mfma_f32_16x16x32_bf16(w3f[0], h2f0, zero4, 0, 0, 0);
    d = __builtin_amdgcn_mfma_f32_16x16x32_bf16(w3f[1], h2f1, d, 0, 0, 0);

    // ---- keep-trick: lane-group lg keeps pass quad*4+lg ----
    keep = (lg == (p & 3)) ? d[0] : keep;
    if ((p & 3) == 3) {
      const int row = rb * kRowsPerWave + (p >> 2) * 64 + lane;
      out[(size_t)row * kF + f] = keep + b3v;
    }
  }
}

}  // namespace

extern "C" void kernel_launch(void* const* d_in, const int* in_sizes, int n_in,
                              void* d_out, int out_size, void* d_ws, size_t ws_size,
                              hipStream_t stream) {
  const float* x  = (const float*)d_in[0];
  const float* w1 = (const float*)d_in[1];
  const float* b1 = (const float*)d_in[2];
  const float* w2 = (const float*)d_in[3];
  const float* b2 = (const float*)d_in[4];
  const float* w3 = (const float*)d_in[5];
  const float* b3 = (const float*)d_in[6];
  float* out = (float*)d_out;

  __bf16* w2p = (__bf16*)d_ws;                           // 2 MB
  float*  b2p = (float*)((char*)d_ws + (2u << 20));      // 64 KB
  __bf16* w3p = (__bf16*)((char*)d_ws + (2u << 20) + (64u << 10));  // 32 KB

  hipLaunchKernelGGL(pack_params, dim3(kF / 4), dim3(256), 0, stream,
                     w2, b2, w3, w2p, b2p, w3p);
  hipLaunchKernelGGL(mlp_pf_v10, dim3(kBlocks), dim3(kThreads), 0, stream,
                     x, w1, b1, w2p, b2p, w3p, b3, out);
}

// Round 11
// 40.370 us; speedup vs baseline: 1.1338x; 1.1338x over previous
//
#include <hip/hip_runtime.h>
#include <hip/hip_bf16.h>

// MLP_small_per_feature: per-feature MLP 1 -> 64 -> 64 -> 1, F=256, B=8192.
// v11 = v9 (best so far, 41.3us) + v10's verified layer3-MFMA trick:
//  - v9 structure: 4 waves/block, coalesced x staging into LDS, outb
//    exchange for coalesced float4 stores, 2-pass ILP pairing,
//    launch_bounds(256,3), kRPB=128, packed L2-resident w2p.
//  - v10 trick (verified, absmax 0.031): w2p packed with OUTPUT rows
//    permuted o'(16t+m) = 32*(t>>1)+8*(m>>2)+4*(t&1)+(m&3) so layer-2's
//    C/D output lands in B-fragment k-slot order; relu+cvt feeds a third
//    MFMA computing layer-3 (A = w3 broadcast across rows). Deletes the 2
//    serial ds_bpermute shuffles + 16 VALU per pass from v9's epilogue.
//  - b3 folded into layer-3 MFMA C operand (splat).
//
// MFMA 16x16x32_bf16 layout (verified rounds 1-10):
//   A: row m = lane&15, k = (lane>>4)*8 + i
//   B: col n = lane&15, k = (lane>>4)*8 + i
//   C/D: col n = lane&15, row m = (lane>>4)*4 + r
// Spill lessons: (256,8) -> VGPR=32 + spills (v6); over-tight state ->
// SGPR=96 / FETCH~=WRITE~=170MB signature (v5,v8). Canaries: SGPR<=48,
// WRITE_SIZE ~= 8MB.

namespace {

constexpr int kF = 256;
constexpr int kH = 64;
constexpr int kB = 8192;

constexpr int kFPB     = 4;               // features per block (one per wave)
constexpr int kRPB     = 128;             // rows per block
constexpr int kThreads = 256;             // 4 waves
constexpr int kFG      = kF / kFPB;       // 64 feature groups
constexpr int kRG      = kB / kRPB;       // 64 row groups
constexpr int kBlocks  = kFG * kRG;       // 4096
constexpr int kPasses  = kRPB / 16;       // 8
constexpr int kXP      = 10;              // xs pass-dim stride: conflict-free

using f32x2  = __attribute__((ext_vector_type(2))) float;
using f32x4  = __attribute__((ext_vector_type(4))) float;
using bf16x4 = __attribute__((ext_vector_type(4))) __bf16;
using bf16x8 = __attribute__((ext_vector_type(8))) __bf16;

// ---- prep: pack w2 (o'-permuted, bf16, fragment-major), b2 (o'-permuted,
// C-layout order), w3 (bf16). One wave per feature. (verified in v10) ----
__global__ __launch_bounds__(256)
void pack_params(const float* __restrict__ w2, const float* __restrict__ b2,
                 const float* __restrict__ w3, __bf16* __restrict__ w2p,
                 float* __restrict__ b2p, __bf16* __restrict__ w3p)
{
  const int wid  = (int)threadIdx.x >> 6;
  const int lane = (int)threadIdx.x & 63;
  const int f    = (int)blockIdx.x * 4 + wid;
  const int l15  = lane & 15;
  const int lg   = lane >> 4;

  const float* w2f = w2 + (size_t)f * (kH * kH);
  #pragma unroll
  for (int t = 0; t < 4; ++t) {
    const int o2 = 32 * (t >> 1) + 8 * (l15 >> 2) + 4 * (t & 1) + (l15 & 3);
    #pragma unroll
    for (int ks = 0; ks < 2; ++ks) {
      const float* p = w2f + o2 * kH + ks * 32 + lg * 8;
      const f32x4 lo = *reinterpret_cast<const f32x4*>(p);
      const f32x4 hi = *reinterpret_cast<const f32x4*>(p + 4);
      const bf16x8 v = __builtin_shufflevector(
          __builtin_convertvector(lo, bf16x4),
          __builtin_convertvector(hi, bf16x4), 0, 1, 2, 3, 4, 5, 6, 7);
      *reinterpret_cast<bf16x8*>(
          w2p + (((size_t)f * 8 + t * 2 + ks) * 64 + lane) * 8) = v;
    }
  }

  {
    const int jt = lane >> 4, jlg = (lane >> 2) & 3, jr = lane & 3;
    const int o  = 32 * (jt >> 1) + 8 * jlg + 4 * (jt & 1) + jr;
    b2p[(size_t)f * kH + lane] = b2[(size_t)f * kH + o];
  }
  w3p[(size_t)f * kH + lane] = (__bf16)w3[(size_t)f * kH + lane];
}

__global__ __launch_bounds__(kThreads, 3)
void mlp_pf_v11(const float* __restrict__ x,
                const float* __restrict__ w1,
                const float* __restrict__ b1,
                const __bf16* __restrict__ w2p,
                const float* __restrict__ b2p,
                const __bf16* __restrict__ w3p,
                const float* __restrict__ b3,
                float* __restrict__ out)
{
  __shared__ float xs[kFPB][16][kXP];     // 2.5 KB [feat][l15][pass]
  __shared__ float outb[kRPB][kFPB + 1];  // 2.56 KB (pad: conflict-free)

  const int tid  = (int)threadIdx.x;
  const int wid  = tid >> 6;
  const int lane = tid & 63;
  const int l15  = lane & 15;
  const int lg   = lane >> 4;

  const int fg = (int)blockIdx.x & (kFG - 1);  // consecutive blocks: same rows
  const int rg = (int)blockIdx.x >> 6;
  const int f  = fg * kFPB + wid;          // this wave's feature
  const int r0 = rg * kRPB;

  // ---- w2 fragments: 8 coalesced 16B loads/lane (L2-resident w2p) ----
  bf16x8 w2frag[4][2];
  {
    const __bf16* base = w2p + ((size_t)f * 8 * 64 + lane) * 8;
    #pragma unroll
    for (int t = 0; t < 4; ++t)
      #pragma unroll
      for (int ks = 0; ks < 2; ++ks)
        w2frag[t][ks] = *reinterpret_cast<const bf16x8*>(
            base + (size_t)(t * 2 + ks) * 64 * 8);
  }

  // ---- stage x tile (128 rows x 4 feats) -> pass-major LDS ----
  if (tid < kRPB) {
    const int rr = tid;
    const f32x4 v = *reinterpret_cast<const f32x4*>(
        x + (size_t)(r0 + rr) * kF + fg * kFPB);
    const int a = rr & 15, b = rr >> 4;
    xs[0][a][b] = v[0]; xs[1][a][b] = v[1];
    xs[2][a][b] = v[2]; xs[3][a][b] = v[3];
  }

  // ---- per-wave params ----
  f32x4 w1v[2][2], b1v[2][2];
  #pragma unroll
  for (int ks = 0; ks < 2; ++ks) {
    const float* pw = w1 + f * kH + ks * 32 + lg * 8;
    const float* pb = b1 + f * kH + ks * 32 + lg * 8;
    w1v[ks][0] = *reinterpret_cast<const f32x4*>(pw);
    w1v[ks][1] = *reinterpret_cast<const f32x4*>(pw + 4);
    b1v[ks][0] = *reinterpret_cast<const f32x4*>(pb);
    b1v[ks][1] = *reinterpret_cast<const f32x4*>(pb + 4);
  }
  f32x4 b2c[4];
  #pragma unroll
  for (int t = 0; t < 4; ++t)
    b2c[t] = *reinterpret_cast<const f32x4*>(b2p + f * kH + t * 16 + lg * 4);
  bf16x8 w3f[2];
  #pragma unroll
  for (int ks = 0; ks < 2; ++ks)
    w3f[ks] = *reinterpret_cast<const bf16x8*>(w3p + f * kH + ks * 32 + lg * 8);
  const float b3v = b3[f];
  const f32x4 b3c = {b3v, b3v, b3v, b3v};

  __syncthreads();   // xs ready

  const f32x4 zero4 = {0.f, 0.f, 0.f, 0.f};
  float keep = 0.f;

  #pragma unroll
  for (int pp = 0; pp < kPasses / 2; ++pp) {
    // both passes' x values in one conflict-free ds_read_b64
    const f32x2 xp = *reinterpret_cast<const f32x2*>(&xs[wid][l15][2 * pp]);

    // ---- layer 1 for both passes (independent chains) ----
    bf16x8 h1A[2], h1B[2];
    #pragma unroll
    for (int ks = 0; ks < 2; ++ks) {
      f32x4 aA = w1v[ks][0] * xp[0] + b1v[ks][0];
      f32x4 bA = w1v[ks][1] * xp[0] + b1v[ks][1];
      f32x4 aB = w1v[ks][0] * xp[1] + b1v[ks][0];
      f32x4 bB = w1v[ks][1] * xp[1] + b1v[ks][1];
      aA = __builtin_elementwise_max(aA, zero4);
      bA = __builtin_elementwise_max(bA, zero4);
      aB = __builtin_elementwise_max(aB, zero4);
      bB = __builtin_elementwise_max(bB, zero4);
      h1A[ks] = __builtin_shufflevector(
          __builtin_convertvector(aA, bf16x4),
          __builtin_convertvector(bA, bf16x4), 0, 1, 2, 3, 4, 5, 6, 7);
      h1B[ks] = __builtin_shufflevector(
          __builtin_convertvector(aB, bf16x4),
          __builtin_convertvector(bB, bf16x4), 0, 1, 2, 3, 4, 5, 6, 7);
    }

    // ---- layer 2 (C = permuted b2), A/B interleaved ----
    f32x4 accA[4], accB[4];
    #pragma unroll
    for (int t = 0; t < 4; ++t) {
      accA[t] = __builtin_amdgcn_mfma_f32_16x16x32_bf16(
          w2frag[t][0], h1A[0], b2c[t], 0, 0, 0);
      accB[t] = __builtin_amdgcn_mfma_f32_16x16x32_bf16(
          w2frag[t][0], h1B[0], b2c[t], 0, 0, 0);
      accA[t] = __builtin_amdgcn_mfma_f32_16x16x32_bf16(
          w2frag[t][1], h1A[1], accA[t], 0, 0, 0);
      accB[t] = __builtin_amdgcn_mfma_f32_16x16x32_bf16(
          w2frag[t][1], h1B[1], accB[t], 0, 0, 0);
    }

    // ---- relu + cvt: acc pairs form B-fragments of the layer-3 MFMA ----
    bf16x8 h2A0, h2A1, h2B0, h2B1;
    {
      const f32x4 rA0 = __builtin_elementwise_max(accA[0], zero4);
      const f32x4 rA1 = __builtin_elementwise_max(accA[1], zero4);
      const f32x4 rA2 = __builtin_elementwise_max(accA[2], zero4);
      const f32x4 rA3 = __builtin_elementwise_max(accA[3], zero4);
      const f32x4 rB0 = __builtin_elementwise_max(accB[0], zero4);
      const f32x4 rB1 = __builtin_elementwise_max(accB[1], zero4);
      const f32x4 rB2 = __builtin_elementwise_max(accB[2], zero4);
      const f32x4 rB3 = __builtin_elementwise_max(accB[3], zero4);
      h2A0 = __builtin_shufflevector(__builtin_convertvector(rA0, bf16x4),
                                     __builtin_convertvector(rA1, bf16x4),
                                     0, 1, 2, 3, 4, 5, 6, 7);
      h2A1 = __builtin_shufflevector(__builtin_convertvector(rA2, bf16x4),
                                     __builtin_convertvector(rA3, bf16x4),
                                     0, 1, 2, 3, 4, 5, 6, 7);
      h2B0 = __builtin_shufflevector(__builtin_convertvector(rB0, bf16x4),
                                     __builtin_convertvector(rB1, bf16x4),
                                     0, 1, 2, 3, 4, 5, 6, 7);
      h2B1 = __builtin_shufflevector(__builtin_convertvector(rB2, bf16x4),
                                     __builtin_convertvector(rB3, bf16x4),
                                     0, 1, 2, 3, 4, 5, 6, 7);
    }

    // ---- layer 3 via MFMA (C = b3 splat); D same across rows ----
    f32x4 dA = __builtin_amdgcn_mfma_f32_16x16x32_bf16(w3f[0], h2A0, b3c, 0, 0, 0);
    f32x4 dB = __builtin_amdgcn_mfma_f32_16x16x32_bf16(w3f[0], h2B0, b3c, 0, 0, 0);
    dA = __builtin_amdgcn_mfma_f32_16x16x32_bf16(w3f[1], h2A1, dA, 0, 0, 0);
    dB = __builtin_amdgcn_mfma_f32_16x16x32_bf16(w3f[1], h2B1, dB, 0, 0, 0);

    // ---- keep-trick: lane-group lg keeps pass quad*4+lg ----
    const int pA = 2 * pp, pB = 2 * pp + 1;
    keep = (lg == (pA & 3)) ? dA[0] : keep;
    keep = (lg == (pB & 3)) ? dB[0] : keep;
    if ((pB & 3) == 3) {
      outb[(pB >> 2) * 64 + lane][wid] = keep;   // b3 already folded in
    }
  }

  __syncthreads();

  // ---- output: one float4 (4 features) per row ----
  if (tid < kRPB) {
    const int rr = tid;
    const f32x4 v = {outb[rr][0], outb[rr][1], outb[rr][2], outb[rr][3]};
    *reinterpret_cast<f32x4*>(out + (size_t)(r0 + rr) * kF + fg * kFPB) = v;
  }
}

}  // namespace

extern "C" void kernel_launch(void* const* d_in, const int* in_sizes, int n_in,
                              void* d_out, int out_size, void* d_ws, size_t ws_size,
                              hipStream_t stream) {
  const float* x  = (const float*)d_in[0];
  const float* w1 = (const float*)d_in[1];
  const float* b1 = (const float*)d_in[2];
  const float* w2 = (const float*)d_in[3];
  const float* b2 = (const float*)d_in[4];
  const float* w3 = (const float*)d_in[5];
  const float* b3 = (const float*)d_in[6];
  float* out = (float*)d_out;

  __bf16* w2p = (__bf16*)d_ws;                           // 2 MB
  float*  b2p = (float*)((char*)d_ws + (2u << 20));      // 64 KB
  __bf16* w3p = (__bf16*)((char*)d_ws + (2u << 20) + (64u << 10));  // 32 KB

  hipLaunchKernelGGL(pack_params, dim3(kF / 4), dim3(256), 0, stream,
                     w2, b2, w3, w2p, b2p, w3p);
  hipLaunchKernelGGL(mlp_pf_v11, dim3(kBlocks), dim3(kThreads), 0, stream,
                     x, w1, b1, w2p, b2p, w3p, b3, out);
}